// Round 3
// baseline (824.437 us; speedup 1.0000x reference)
//
#include <hip/hip_runtime.h>
#include <hip/hip_cooperative_groups.h>

namespace cg = cooperative_groups;

#define DEPTH 18
#define EMB 128
#define HID 256
#define VAL 32
#define N_LEAVES (1 << DEPTH)
#define LEAF_START (N_LEAVES - 1)

typedef _Float16 half8 __attribute__((ext_vector_type(8)));
typedef _Float16 half4 __attribute__((ext_vector_type(4)));
typedef float f32x4 __attribute__((ext_vector_type(4)));

__device__ __forceinline__ float lrelu(float x) { return x > 0.f ? x : 0.01f * x; }

// ---------------------------------------------------------------------------
// Prep: swizzle W1 (256x256) and W2 (256x128) into fp16 MFMA A-fragment order
// for the TRANSPOSED GEMMs (A = W^T, m = output col, k = contraction dim).
// Emits BOTH hi (f16 rounding of W) and lo (f16 of residual W - hi) frags:
// the lo arrays feed the split-precision tail so the last 6 levels stay at
// effectively-fp32 accuracy while using MFMA.
// Frag lane layout (16x16x32): lane holds A[m = lane&15][k = (lane>>4)*8 + jj].
// ---------------------------------------------------------------------------
__global__ __launch_bounds__(256) void prep_weights(
    const float* __restrict__ W1, const float* __restrict__ W2,
    _Float16* __restrict__ W1f, _Float16* __restrict__ W2f,
    _Float16* __restrict__ W1l, _Float16* __restrict__ W2l)
{
    const int gid = blockIdx.x * 256 + threadIdx.x;   // 12288 total (8192 + 4096)
    const int lane = gid & 63;
    const int nn = lane & 15, q = lane >> 4;
    if (gid < 8192) {
        const int f = gid >> 6, kb = f >> 4, jt = f & 15;
        half8 vh, vl;
#pragma unroll
        for (int jj = 0; jj < 8; ++jj) {
            float x = W1[(kb * 32 + q * 8 + jj) * HID + jt * 16 + nn];
            _Float16 h = (_Float16)x;
            vh[jj] = h;
            vl[jj] = (_Float16)(x - (float)h);
        }
        *((half8*)W1f + gid) = vh;
        *((half8*)W1l + gid) = vl;
    } else {
        const int g = gid - 8192;
        const int f = g >> 6, kb = f >> 3, ct = f & 7;
        half8 vh, vl;
#pragma unroll
        for (int jj = 0; jj < 8; ++jj) {
            float x = W2[(kb * 32 + q * 8 + jj) * EMB + ct * 16 + nn];
            _Float16 h = (_Float16)x;
            vh[jj] = h;
            vl[jj] = (_Float16)(x - (float)h);
        }
        *((half8*)W2f + g) = vh;
        *((half8*)W2l + g) = vl;
    }
}

// ---------------------------------------------------------------------------
// Leaf embedding: lrelu(leaf_values @ We + be) -> embs[LEAF_START..] (fp32)
// ---------------------------------------------------------------------------
__global__ __launch_bounds__(256) void leaf_embed(
    const float* __restrict__ lv, const float* __restrict__ We,
    const float* __restrict__ be, float* __restrict__ embs)
{
    __shared__ float lvs[16][VAL];
    const int j = threadIdx.x & 127;
    const int h = threadIdx.x >> 7;

    float w[VAL];
#pragma unroll
    for (int k = 0; k < VAL; ++k) w[k] = We[k * EMB + j];
    const float bj = be[j];

    const int leaf0 = blockIdx.x * 16;
    {
        const float* src = lv + (size_t)leaf0 * VAL;
        ((float*)lvs)[threadIdx.x]       = src[threadIdx.x];
        ((float*)lvs)[threadIdx.x + 256] = src[threadIdx.x + 256];
    }
    __syncthreads();

#pragma unroll
    for (int it = 0; it < 8; ++it) {
        const int ll = it * 2 + h;
        float acc = bj;
#pragma unroll
        for (int k4 = 0; k4 < VAL / 4; ++k4) {
            float4 x4 = *(const float4*)&lvs[ll][k4 * 4];
            acc += x4.x * w[k4*4] + x4.y * w[k4*4+1] + x4.z * w[k4*4+2] + x4.w * w[k4*4+3];
        }
        embs[(size_t)(LEAF_START + leaf0 + ll) * EMB + j] = lrelu(acc);
    }
}

// ---------------------------------------------------------------------------
// Cooperative megakernel: ALL levels 17..6 in one launch, grid.sync between
// levels. 256 blocks x 512 threads (8 waves). Weight-stationary dataflow:
//   wave w holds W1 jt tiles {2w, 2w+1} (16 frags = 64 VGPR) and W2 ct tile w
//   (8 frags = 32 VGPR) in registers for the WHOLE kernel -> zero weight
//   re-reads (the round-2 ladder re-read 192 KB/wave per 16 rows from L2,
//   which serialized the small levels at ~50-60 us each).
// Per 64-row strip (grid-strided within a level):
//   stage:  children X (64 rows x 256 f32, contiguous) -> LDS f16 [64][264]
//   GEMM1:  H^T = W1^T @ X^T ; each wave its 2 hid tiles for all 64 rows
//   H epilogue: lrelu -> f16 -> Hs[64][264] (cross-wave exchange)
//   GEMM2:  O^T = W2^T @ H^T ; each wave its 16 out-cols for all 64 rows
//   O epilogue: lrelu -> fp32 embs
// 2-way LDS bank aliasing max (row stride 264 f16 = 132 words; free per m136).
// ---------------------------------------------------------------------------
__global__ __launch_bounds__(512) void ladder_mfma(
    const _Float16* __restrict__ W1f, const _Float16* __restrict__ W2f,
    const float* __restrict__ b1, const float* __restrict__ b2,
    float* __restrict__ embs)
{
    __shared__ alignas(16) _Float16 Xs[64][264];   // 33792 B
    __shared__ alignas(16) _Float16 Hs[64][264];   // 33792 B  (67.6 KB total)

    cg::grid_group grid = cg::this_grid();

    const int tid  = threadIdx.x;
    const int w    = tid >> 6;        // 0..7
    const int lane = tid & 63;
    const int nl   = lane & 15;
    const int q    = lane >> 4;

    // ---- one-time weight preload into registers ----
    half8 w1[8][2], w2[8];
#pragma unroll
    for (int kb = 0; kb < 8; ++kb) {
#pragma unroll
        for (int j = 0; j < 2; ++j)
            w1[kb][j] = ((const half8*)W1f)[(kb * 16 + 2 * w + j) * 64 + lane];
        w2[kb] = ((const half8*)W2f)[(kb * 8 + w) * 64 + lane];
    }
    // ---- bias fragments (loop-invariant) ----
    f32x4 bb1[2], bb2;
#pragma unroll
    for (int j = 0; j < 2; ++j)
        bb1[j] = *(const f32x4*)(b1 + (2 * w + j) * 16 + q * 4);
    bb2 = *(const f32x4*)(b2 + w * 16 + q * 4);

#pragma unroll 1
    for (int l = DEPTH - 1; l >= 6; --l) {
        const int p0 = (1 << l) - 1;
        const int nstrips = 1 << (l - 6);          // strips of 64 parent rows

#pragma unroll 1
        for (int s0 = blockIdx.x; s0 < nstrips; s0 += gridDim.x) {
            // ---- stage: children of this strip (contiguous 64 KB) -> f16 LDS ----
            const float* xb = embs + ((size_t)(2 * p0 + 1) + (size_t)128 * s0) * EMB;
            const float4* src = (const float4*)xb;
#pragma unroll
            for (int i = 0; i < 8; ++i) {
                const int f = i * 512 + tid;       // 0..4095 float4s
                float4 v = src[f];
                half4 h;
                h[0] = (_Float16)v.x; h[1] = (_Float16)v.y;
                h[2] = (_Float16)v.z; h[3] = (_Float16)v.w;
                *(half4*)&Xs[f >> 6][(f & 63) * 4] = h;
            }
            __syncthreads();                        // A: Xs ready, prev GEMM2 done

            // ---- GEMM1': H^T = W1^T @ X^T ----
            f32x4 d1[4][2];
#pragma unroll
            for (int s = 0; s < 4; ++s) { d1[s][0] = bb1[0]; d1[s][1] = bb1[1]; }
#pragma unroll
            for (int kb = 0; kb < 8; ++kb) {
#pragma unroll
                for (int s = 0; s < 4; ++s) {
                    half8 x = *(const half8*)&Xs[s * 16 + nl][kb * 32 + q * 8];
                    d1[s][0] = __builtin_amdgcn_mfma_f32_16x16x32_f16(w1[kb][0], x, d1[s][0], 0, 0, 0);
                    d1[s][1] = __builtin_amdgcn_mfma_f32_16x16x32_f16(w1[kb][1], x, d1[s][1], 0, 0, 0);
                }
            }
            // ---- epilogue 1: lrelu -> f16 -> Hs (cross-wave) ----
#pragma unroll
            for (int s = 0; s < 4; ++s) {
#pragma unroll
                for (int j = 0; j < 2; ++j) {
                    half4 h;
#pragma unroll
                    for (int r = 0; r < 4; ++r) {
                        float x = d1[s][j][r];
                        h[r] = (_Float16)(x > 0.f ? x : 0.01f * x);
                    }
                    *(half4*)&Hs[s * 16 + nl][(2 * w + j) * 16 + q * 4] = h;
                }
            }
            __syncthreads();                        // B: Hs ready, Xs reads done

            // ---- GEMM2': O^T = W2^T @ H^T ----
            f32x4 d2[4];
#pragma unroll
            for (int s = 0; s < 4; ++s) d2[s] = bb2;
#pragma unroll
            for (int kb = 0; kb < 8; ++kb) {
#pragma unroll
                for (int s = 0; s < 4; ++s) {
                    half8 h = *(const half8*)&Hs[s * 16 + nl][kb * 32 + q * 8];
                    d2[s] = __builtin_amdgcn_mfma_f32_16x16x32_f16(w2[kb], h, d2[s], 0, 0, 0);
                }
            }
            // ---- epilogue 2: lrelu -> fp32 embs ----
            float* obase = embs + ((size_t)p0 + (size_t)64 * s0) * EMB;
#pragma unroll
            for (int s = 0; s < 4; ++s) {
                f32x4 o;
#pragma unroll
                for (int r = 0; r < 4; ++r) {
                    float x = d2[s][r];
                    o[r] = x > 0.f ? x : 0.01f * x;
                }
                *(f32x4*)(obase + (s * 16 + nl) * EMB + w * 16 + q * 4) = o;
            }
        }
        grid.sync();                                // level l complete everywhere
    }
}

// ---------------------------------------------------------------------------
// Levels 5..0 (63 nodes) fused in ONE 8-wave block, split-precision f16 MFMA
// (acc += xh*wh + xl*wh + xh*wl -> ~fp32 accuracy, rel err ~2^-22).
// Weights REGISTER-RESIDENT (hi+lo), loaded once. Activations ping-pong in
// LDS as f16 hi/lo pairs. See round-2 notes; unchanged (measured ~40 us).
// ---------------------------------------------------------------------------
__global__ __launch_bounds__(512, 2) void tail_levels(
    const _Float16* __restrict__ W1f, const _Float16* __restrict__ W1l,
    const _Float16* __restrict__ W2f, const _Float16* __restrict__ W2l,
    const float* __restrict__ b1, const float* __restrict__ b2,
    float* __restrict__ embs)
{
    __shared__ alignas(16) _Float16 Hsh[32][264];      // 16896 B
    __shared__ alignas(16) _Float16 Hsl[32][264];      // 16896 B
    __shared__ alignas(16) _Float16 Obh[2][16][136];   //  8704 B
    __shared__ alignas(16) _Float16 Obl[2][16][136];   //  8704 B   (51.2 KB)

    const int tid  = threadIdx.x;
    const int w    = tid >> 6;        // 0..7
    const int lane = tid & 63;
    const int nl   = lane & 15;
    const int q    = lane >> 4;

    // ---- one-time weight preload into registers (static indexing only) ----
    half8 w1h[8][2], w1l[8][2], w2h[8], w2l[8];
#pragma unroll
    for (int kb = 0; kb < 8; ++kb) {
#pragma unroll
        for (int j = 0; j < 2; ++j) {
            const int f = kb * 16 + (2 * w + j);
            w1h[kb][j] = ((const half8*)W1f)[f * 64 + lane];
            w1l[kb][j] = ((const half8*)W1l)[f * 64 + lane];
        }
        const int g = kb * 8 + w;
        w2h[kb] = ((const half8*)W2f)[g * 64 + lane];
        w2l[kb] = ((const half8*)W2l)[g * 64 + lane];
    }

#pragma unroll 1
    for (int l = 5; l >= 0; --l) {
        const int p0 = (1 << l) - 1, n = 1 << l;
        const int ns = (l == 5) ? 2 : 1;     // strips of 16 rows (uniform)

        // ---- GEMM1': H^T = W1^T @ X^T, bias-init, split f16 ----
        f32x4 d1[2][2];
#pragma unroll
        for (int s = 0; s < 2; ++s)
#pragma unroll
            for (int j = 0; j < 2; ++j)
                d1[s][j] = *(const f32x4*)(b1 + (2 * w + j) * 16 + q * 4);

#pragma unroll
        for (int kb = 0; kb < 8; ++kb) {
            const int k0  = kb * 32 + q * 8;        // 0..255, 8-aligned
            const int hi  = kb >> 2;                // which child half
            const int col = (kb & 3) * 32 + q * 8;  // col within child
#pragma unroll
            for (int s = 0; s < 2; ++s) {
                if (s >= ns) break;
                half8 xh, xl;
                if (l == 5) {
                    const int row = s * 16 + nl;
                    const float* Xr = embs + (size_t)(63 + 2 * row) * EMB + k0;
                    f32x4 u = *(const f32x4*)Xr;
                    f32x4 v = *(const f32x4*)(Xr + 4);
#pragma unroll
                    for (int r = 0; r < 4; ++r) {
                        _Float16 a = (_Float16)u[r];
                        xh[r] = a; xl[r] = (_Float16)(u[r] - (float)a);
                        _Float16 b = (_Float16)v[r];
                        xh[r + 4] = b; xl[r + 4] = (_Float16)(v[r] - (float)b);
                    }
                } else {
                    // child = (2*row + hi) & 31 = 2*nl + hi  (independent of s)
                    xh = *(const half8*)&Obh[hi][nl][col];
                    xl = *(const half8*)&Obl[hi][nl][col];
                }
#pragma unroll
                for (int j = 0; j < 2; ++j) {
                    d1[s][j] = __builtin_amdgcn_mfma_f32_16x16x32_f16(w1h[kb][j], xh, d1[s][j], 0, 0, 0);
                    d1[s][j] = __builtin_amdgcn_mfma_f32_16x16x32_f16(w1h[kb][j], xl, d1[s][j], 0, 0, 0);
                    d1[s][j] = __builtin_amdgcn_mfma_f32_16x16x32_f16(w1l[kb][j], xh, d1[s][j], 0, 0, 0);
                }
            }
        }

        // ---- epilogue 1: lrelu, hi/lo f16, store H to LDS (cross-wave) ----
#pragma unroll
        for (int s = 0; s < 2; ++s) {
            if (s >= ns) break;
            const int row = s * 16 + nl;
#pragma unroll
            for (int j = 0; j < 2; ++j) {
                half4 hh4, hl4;
#pragma unroll
                for (int r = 0; r < 4; ++r) {
                    float x = d1[s][j][r];
                    x = x > 0.f ? x : 0.01f * x;
                    _Float16 a = (_Float16)x;
                    hh4[r] = a; hl4[r] = (_Float16)(x - (float)a);
                }
                const int cf = (2 * w + j) * 16 + q * 4;
                *(half4*)&Hsh[row][cf] = hh4;
                *(half4*)&Hsl[row][cf] = hl4;
            }
        }
        __syncthreads();

        // ---- GEMM2': O^T = W2^T @ H^T, split f16 ----
        f32x4 d2[2];
#pragma unroll
        for (int s = 0; s < 2; ++s)
            d2[s] = *(const f32x4*)(b2 + w * 16 + q * 4);

#pragma unroll
        for (int kb = 0; kb < 8; ++kb) {
#pragma unroll
            for (int s = 0; s < 2; ++s) {
                if (s >= ns) break;
                const int row = s * 16 + nl;
                half8 hh = *(const half8*)&Hsh[row][kb * 32 + q * 8];
                half8 hl = *(const half8*)&Hsl[row][kb * 32 + q * 8];
                d2[s] = __builtin_amdgcn_mfma_f32_16x16x32_f16(w2h[kb], hh, d2[s], 0, 0, 0);
                d2[s] = __builtin_amdgcn_mfma_f32_16x16x32_f16(w2h[kb], hl, d2[s], 0, 0, 0);
                d2[s] = __builtin_amdgcn_mfma_f32_16x16x32_f16(w2l[kb], hh, d2[s], 0, 0, 0);
            }
        }

        // ---- epilogue 2: lrelu; O to parity-split LDS + global for row<n ----
#pragma unroll
        for (int s = 0; s < 2; ++s) {
            if (s >= ns) break;
            const int row = s * 16 + nl;
            f32x4 o;
#pragma unroll
            for (int r = 0; r < 4; ++r) { float x = d2[s][r]; o[r] = x > 0.f ? x : 0.01f * x; }
            half4 oh4, ol4;
#pragma unroll
            for (int r = 0; r < 4; ++r) {
                _Float16 a = (_Float16)o[r];
                oh4[r] = a; ol4[r] = (_Float16)(o[r] - (float)a);
            }
            const int cf = w * 16 + q * 4;
            *(half4*)&Obh[row & 1][row >> 1][cf] = oh4;
            *(half4*)&Obl[row & 1][row >> 1][cf] = ol4;
            if (row < n)
                *(f32x4*)(embs + (size_t)(p0 + row) * EMB + cf) = o;
        }
        __syncthreads();
    }
}

// ---------------------------------------------------------------------------
extern "C" void kernel_launch(void* const* d_in, const int* in_sizes, int n_in,
                              void* d_out, int out_size, void* d_ws, size_t ws_size,
                              hipStream_t stream)
{
    const float* lv = (const float*)d_in[0];
    const float* We = (const float*)d_in[1];
    const float* be = (const float*)d_in[2];
    const float* W1 = (const float*)d_in[3];
    const float* b1 = (const float*)d_in[4];
    const float* W2 = (const float*)d_in[5];
    const float* b2 = (const float*)d_in[6];
    float* embs = (float*)d_out;

    _Float16* W1f = (_Float16*)d_ws;            // 65536 f16 = 128 KB
    _Float16* W2f = W1f + 65536;                // 32768 f16 =  64 KB
    _Float16* W1l = W2f + 32768;                // 65536 f16 = 128 KB
    _Float16* W2l = W1l + 65536;                // 32768 f16 =  64 KB  (384 KB total)

    prep_weights<<<48, 256, 0, stream>>>(W1, W2, W1f, W2f, W1l, W2l);
    leaf_embed<<<N_LEAVES / 16, 256, 0, stream>>>(lv, We, be, embs);

    {
        void* args[] = {(void*)&W1f, (void*)&W2f, (void*)&b1, (void*)&b2, (void*)&embs};
        hipLaunchCooperativeKernel((void*)ladder_mfma, dim3(256), dim3(512),
                                   args, 0, stream);
    }

    tail_levels<<<1, 512, 0, stream>>>(W1f, W1l, W2f, W2l, b1, b2, embs);
}

// Round 4
// 462.932 us; speedup vs baseline: 1.7809x; 1.7809x over previous
//
#include <hip/hip_runtime.h>

#define DEPTH 18
#define EMB 128
#define HID 256
#define VAL 32
#define N_LEAVES (1 << DEPTH)
#define LEAF_START (N_LEAVES - 1)

typedef _Float16 half8 __attribute__((ext_vector_type(8)));
typedef _Float16 half4 __attribute__((ext_vector_type(4)));
typedef float f32x4 __attribute__((ext_vector_type(4)));

__device__ __forceinline__ float lrelu(float x) { return x > 0.f ? x : 0.01f * x; }

// ---------------------------------------------------------------------------
// Prep: swizzle W1 (256x256) and W2 (256x128) into fp16 MFMA A-fragment order
// for the TRANSPOSED GEMMs (A = W^T, m = output col, k = contraction dim).
// Emits BOTH hi (f16 rounding of W) and lo (f16 of residual W - hi) frags:
// the lo arrays feed the split-precision tail so the last 6 levels stay at
// effectively-fp32 accuracy while using MFMA.
// Frag lane layout (16x16x32): lane holds A[m = lane&15][k = (lane>>4)*8 + jj].
// ---------------------------------------------------------------------------
__global__ __launch_bounds__(256) void prep_weights(
    const float* __restrict__ W1, const float* __restrict__ W2,
    _Float16* __restrict__ W1f, _Float16* __restrict__ W2f,
    _Float16* __restrict__ W1l, _Float16* __restrict__ W2l)
{
    const int gid = blockIdx.x * 256 + threadIdx.x;   // 12288 total (8192 + 4096)
    const int lane = gid & 63;
    const int nn = lane & 15, q = lane >> 4;
    if (gid < 8192) {
        const int f = gid >> 6, kb = f >> 4, jt = f & 15;
        half8 vh, vl;
#pragma unroll
        for (int jj = 0; jj < 8; ++jj) {
            float x = W1[(kb * 32 + q * 8 + jj) * HID + jt * 16 + nn];
            _Float16 h = (_Float16)x;
            vh[jj] = h;
            vl[jj] = (_Float16)(x - (float)h);
        }
        *((half8*)W1f + gid) = vh;
        *((half8*)W1l + gid) = vl;
    } else {
        const int g = gid - 8192;
        const int f = g >> 6, kb = f >> 3, ct = f & 7;
        half8 vh, vl;
#pragma unroll
        for (int jj = 0; jj < 8; ++jj) {
            float x = W2[(kb * 32 + q * 8 + jj) * EMB + ct * 16 + nn];
            _Float16 h = (_Float16)x;
            vh[jj] = h;
            vl[jj] = (_Float16)(x - (float)h);
        }
        *((half8*)W2f + g) = vh;
        *((half8*)W2l + g) = vl;
    }
}

// ---------------------------------------------------------------------------
// Leaf embedding: lrelu(leaf_values @ We + be) -> embs[LEAF_START..] (fp32)
// ---------------------------------------------------------------------------
__global__ __launch_bounds__(256) void leaf_embed(
    const float* __restrict__ lv, const float* __restrict__ We,
    const float* __restrict__ be, float* __restrict__ embs)
{
    __shared__ float lvs[16][VAL];
    const int j = threadIdx.x & 127;
    const int h = threadIdx.x >> 7;

    float w[VAL];
#pragma unroll
    for (int k = 0; k < VAL; ++k) w[k] = We[k * EMB + j];
    const float bj = be[j];

    const int leaf0 = blockIdx.x * 16;
    {
        const float* src = lv + (size_t)leaf0 * VAL;
        ((float*)lvs)[threadIdx.x]       = src[threadIdx.x];
        ((float*)lvs)[threadIdx.x + 256] = src[threadIdx.x + 256];
    }
    __syncthreads();

#pragma unroll
    for (int it = 0; it < 8; ++it) {
        const int ll = it * 2 + h;
        float acc = bj;
#pragma unroll
        for (int k4 = 0; k4 < VAL / 4; ++k4) {
            float4 x4 = *(const float4*)&lvs[ll][k4 * 4];
            acc += x4.x * w[k4*4] + x4.y * w[k4*4+1] + x4.z * w[k4*4+2] + x4.w * w[k4*4+3];
        }
        embs[(size_t)(LEAF_START + leaf0 + ll) * EMB + j] = lrelu(acc);
    }
}

// ---------------------------------------------------------------------------
// One 64-parent-row strip, staged-LDS fp16 MFMA dataflow (8 waves, wave w owns
// W1 hid tiles {2w,2w+1} and W2 out-col tile w, register-resident).
// Ends with __syncthreads() so the fp32 output stores are retired to L2
// before ANY wave of this block stages a dependent child read (intra-block
// level->level RAW goes through the same XCD L2 -> coherent).
// ---------------------------------------------------------------------------
__device__ __forceinline__ void strip64(
    const half8 (&w1)[8][2], const half8 (&w2)[8],
    const f32x4 (&bb1)[2], const f32x4 bb2,
    float* __restrict__ embs, int p0, int r0,
    _Float16 (&Xs)[64][264], _Float16 (&Hs)[64][264],
    int tid, int w, int nl, int q)
{
    // ---- stage: children rows [2*r0, 2*r0+128) of next level -> f16 LDS ----
    const float4* src = (const float4*)(embs + ((size_t)(2 * p0 + 1) + 2 * (size_t)r0) * EMB);
#pragma unroll
    for (int i = 0; i < 8; ++i) {
        const int f = i * 512 + tid;       // 0..4095 float4s
        float4 v = src[f];
        half4 h;
        h[0] = (_Float16)v.x; h[1] = (_Float16)v.y;
        h[2] = (_Float16)v.z; h[3] = (_Float16)v.w;
        *(half4*)&Xs[f >> 6][(f & 63) * 4] = h;
    }
    __syncthreads();                        // Xs ready

    // ---- GEMM1': H^T = W1^T @ X^T ----
    f32x4 d1[4][2];
#pragma unroll
    for (int s = 0; s < 4; ++s) { d1[s][0] = bb1[0]; d1[s][1] = bb1[1]; }
#pragma unroll
    for (int kb = 0; kb < 8; ++kb) {
#pragma unroll
        for (int s = 0; s < 4; ++s) {
            half8 x = *(const half8*)&Xs[s * 16 + nl][kb * 32 + q * 8];
            d1[s][0] = __builtin_amdgcn_mfma_f32_16x16x32_f16(w1[kb][0], x, d1[s][0], 0, 0, 0);
            d1[s][1] = __builtin_amdgcn_mfma_f32_16x16x32_f16(w1[kb][1], x, d1[s][1], 0, 0, 0);
        }
    }
    // ---- epilogue 1: lrelu -> f16 -> Hs (cross-wave exchange) ----
#pragma unroll
    for (int s = 0; s < 4; ++s) {
#pragma unroll
        for (int j = 0; j < 2; ++j) {
            half4 h;
#pragma unroll
            for (int r = 0; r < 4; ++r) {
                float x = d1[s][j][r];
                h[r] = (_Float16)(x > 0.f ? x : 0.01f * x);
            }
            *(half4*)&Hs[s * 16 + nl][(2 * w + j) * 16 + q * 4] = h;
        }
    }
    __syncthreads();                        // Hs ready

    // ---- GEMM2': O^T = W2^T @ H^T ----
    f32x4 d2[4];
#pragma unroll
    for (int s = 0; s < 4; ++s) d2[s] = bb2;
#pragma unroll
    for (int kb = 0; kb < 8; ++kb) {
#pragma unroll
        for (int s = 0; s < 4; ++s) {
            half8 h = *(const half8*)&Hs[s * 16 + nl][kb * 32 + q * 8];
            d2[s] = __builtin_amdgcn_mfma_f32_16x16x32_f16(w2[kb], h, d2[s], 0, 0, 0);
        }
    }
    // ---- epilogue 2: lrelu -> fp32 embs ----
    float* obase = embs + ((size_t)p0 + r0) * EMB;
#pragma unroll
    for (int s = 0; s < 4; ++s) {
        f32x4 o;
#pragma unroll
        for (int r = 0; r < 4; ++r) {
            float x = d2[s][r];
            o[r] = x > 0.f ? x : 0.01f * x;
        }
        *(f32x4*)(obase + (s * 16 + nl) * EMB + w * 16 + q * 4) = o;
    }
    __syncthreads();   // stores in L2 before next strip/level stages from them
}

// ---------------------------------------------------------------------------
// Upper ladder: levels 17..8, NO grid sync. Block b owns the aligned subtree
// over level-17 rows [512b, 512b+512): every level down to l=8 (1 row/block)
// depends only on this block's own children -> pure intra-block barriers.
// (Round-3 post-mortem: cg::grid.sync() cost ~35 us each, 420/484 us total.)
// Levels with R>=64 rows/block: staged-LDS strip64. Levels with R<64
// (l=13..8): per-lane global X reads (same-XCD L2 hits), 16-row tiles,
// garbage rows (beyond R) read in-bounds junk and are write-guarded.
// MFMA sequence per real output element is bit-identical to round 3.
// ---------------------------------------------------------------------------
__global__ __launch_bounds__(512) void upper_ladder(
    const _Float16* __restrict__ W1f, const _Float16* __restrict__ W2f,
    const float* __restrict__ b1, const float* __restrict__ b2,
    float* __restrict__ embs)
{
    __shared__ alignas(16) _Float16 Xs[64][264];   // 33792 B
    __shared__ alignas(16) _Float16 Hs[64][264];   // 33792 B

    const int tid  = threadIdx.x;
    const int w    = tid >> 6;        // 0..7
    const int lane = tid & 63;
    const int nl   = lane & 15;
    const int q    = lane >> 4;
    const int b    = blockIdx.x;      // 0..255 subtree id

    // ---- one-time weight preload into registers ----
    half8 w1[8][2], w2[8];
#pragma unroll
    for (int kb = 0; kb < 8; ++kb) {
#pragma unroll
        for (int j = 0; j < 2; ++j)
            w1[kb][j] = ((const half8*)W1f)[(kb * 16 + 2 * w + j) * 64 + lane];
        w2[kb] = ((const half8*)W2f)[(kb * 8 + w) * 64 + lane];
    }
    f32x4 bb1[2], bb2;
#pragma unroll
    for (int j = 0; j < 2; ++j)
        bb1[j] = *(const f32x4*)(b1 + (2 * w + j) * 16 + q * 4);
    bb2 = *(const f32x4*)(b2 + w * 16 + q * 4);

#pragma unroll 1
    for (int l = DEPTH - 1; l >= 8; --l) {
        const int p0 = (1 << l) - 1;
        const int R  = 1 << (l - 8);           // rows per block at this level
        const int row0 = R * b;

        if (R >= 64) {
#pragma unroll 1
            for (int t = 0; t < (R >> 6); ++t)
                strip64(w1, w2, bb1, bb2, embs, p0, row0 + t * 64,
                        Xs, Hs, tid, w, nl, q);
        } else {
            const int ns = (R > 16) ? 2 : 1;   // 16-row tiles (R=32 -> 2)

            // ---- GEMM1': per-lane global X (same-XCD L2), hi-only f16 ----
            f32x4 d1[2][2];
#pragma unroll
            for (int s = 0; s < 2; ++s) { d1[s][0] = bb1[0]; d1[s][1] = bb1[1]; }
#pragma unroll
            for (int kb = 0; kb < 8; ++kb) {
#pragma unroll
                for (int s = 0; s < 2; ++s) {
                    if (s >= ns) break;
                    const int row = row0 + s * 16 + nl;   // may be garbage (>=R)
                    const float* Xr = embs + (size_t)(2 * (p0 + row) + 1) * EMB
                                    + kb * 32 + q * 8;
                    f32x4 u = *(const f32x4*)Xr;
                    f32x4 v = *(const f32x4*)(Xr + 4);
                    half8 x;
#pragma unroll
                    for (int r = 0; r < 4; ++r) {
                        x[r]     = (_Float16)u[r];
                        x[r + 4] = (_Float16)v[r];
                    }
                    d1[s][0] = __builtin_amdgcn_mfma_f32_16x16x32_f16(w1[kb][0], x, d1[s][0], 0, 0, 0);
                    d1[s][1] = __builtin_amdgcn_mfma_f32_16x16x32_f16(w1[kb][1], x, d1[s][1], 0, 0, 0);
                }
            }
            // ---- epilogue 1 (preceded by a barrier in all paths -> safe) ----
#pragma unroll
            for (int s = 0; s < 2; ++s) {
                if (s >= ns) break;
#pragma unroll
                for (int j = 0; j < 2; ++j) {
                    half4 h;
#pragma unroll
                    for (int r = 0; r < 4; ++r) {
                        float x = d1[s][j][r];
                        h[r] = (_Float16)(x > 0.f ? x : 0.01f * x);
                    }
                    *(half4*)&Hs[s * 16 + nl][(2 * w + j) * 16 + q * 4] = h;
                }
            }
            __syncthreads();                    // Hs ready

            // ---- GEMM2' ----
            f32x4 d2[2];
#pragma unroll
            for (int s = 0; s < 2; ++s) d2[s] = bb2;
#pragma unroll
            for (int kb = 0; kb < 8; ++kb) {
#pragma unroll
                for (int s = 0; s < 2; ++s) {
                    if (s >= ns) break;
                    half8 h = *(const half8*)&Hs[s * 16 + nl][kb * 32 + q * 8];
                    d2[s] = __builtin_amdgcn_mfma_f32_16x16x32_f16(w2[kb], h, d2[s], 0, 0, 0);
                }
            }
            // ---- epilogue 2: guarded fp32 writes (garbage rows dropped) ----
#pragma unroll
            for (int s = 0; s < 2; ++s) {
                if (s >= ns) break;
                const int idx = s * 16 + nl;
                f32x4 o;
#pragma unroll
                for (int r = 0; r < 4; ++r) {
                    float x = d2[s][r];
                    o[r] = x > 0.f ? x : 0.01f * x;
                }
                if (idx < R)
                    *(f32x4*)(embs + (size_t)(p0 + row0 + idx) * EMB + w * 16 + q * 4) = o;
            }
            __syncthreads();                    // level complete (L2-visible)
        }
    }
}

// ---------------------------------------------------------------------------
// Mid ladder: levels 7,6 (one block, three strip64 calls). Children of level
// 7 come from upper_ladder (cross-kernel dispatch boundary -> visible);
// level 6's children come from this block's own level-7 strips (barrier'd).
// ---------------------------------------------------------------------------
__global__ __launch_bounds__(512) void mid_ladder(
    const _Float16* __restrict__ W1f, const _Float16* __restrict__ W2f,
    const float* __restrict__ b1, const float* __restrict__ b2,
    float* __restrict__ embs)
{
    __shared__ alignas(16) _Float16 Xs[64][264];
    __shared__ alignas(16) _Float16 Hs[64][264];

    const int tid  = threadIdx.x;
    const int w    = tid >> 6;
    const int lane = tid & 63;
    const int nl   = lane & 15;
    const int q    = lane >> 4;

    half8 w1[8][2], w2[8];
#pragma unroll
    for (int kb = 0; kb < 8; ++kb) {
#pragma unroll
        for (int j = 0; j < 2; ++j)
            w1[kb][j] = ((const half8*)W1f)[(kb * 16 + 2 * w + j) * 64 + lane];
        w2[kb] = ((const half8*)W2f)[(kb * 8 + w) * 64 + lane];
    }
    f32x4 bb1[2], bb2;
#pragma unroll
    for (int j = 0; j < 2; ++j)
        bb1[j] = *(const f32x4*)(b1 + (2 * w + j) * 16 + q * 4);
    bb2 = *(const f32x4*)(b2 + w * 16 + q * 4);

    strip64(w1, w2, bb1, bb2, embs, 127,  0, Xs, Hs, tid, w, nl, q);  // l=7 a
    strip64(w1, w2, bb1, bb2, embs, 127, 64, Xs, Hs, tid, w, nl, q);  // l=7 b
    strip64(w1, w2, bb1, bb2, embs,  63,  0, Xs, Hs, tid, w, nl, q);  // l=6
}

// ---------------------------------------------------------------------------
// Levels 5..0 (63 nodes) fused in ONE 8-wave block, split-precision f16 MFMA
// (acc += xh*wh + xl*wh + xh*wl -> ~fp32 accuracy, rel err ~2^-22).
// Weights REGISTER-RESIDENT (hi+lo), loaded once. Activations ping-pong in
// LDS as f16 hi/lo pairs. Unchanged since round 2 (measured ~40 us).
// ---------------------------------------------------------------------------
__global__ __launch_bounds__(512, 2) void tail_levels(
    const _Float16* __restrict__ W1f, const _Float16* __restrict__ W1l,
    const _Float16* __restrict__ W2f, const _Float16* __restrict__ W2l,
    const float* __restrict__ b1, const float* __restrict__ b2,
    float* __restrict__ embs)
{
    __shared__ alignas(16) _Float16 Hsh[32][264];      // 16896 B
    __shared__ alignas(16) _Float16 Hsl[32][264];      // 16896 B
    __shared__ alignas(16) _Float16 Obh[2][16][136];   //  8704 B
    __shared__ alignas(16) _Float16 Obl[2][16][136];   //  8704 B   (51.2 KB)

    const int tid  = threadIdx.x;
    const int w    = tid >> 6;        // 0..7
    const int lane = tid & 63;
    const int nl   = lane & 15;
    const int q    = lane >> 4;

    // ---- one-time weight preload into registers (static indexing only) ----
    half8 w1h[8][2], w1l[8][2], w2h[8], w2l[8];
#pragma unroll
    for (int kb = 0; kb < 8; ++kb) {
#pragma unroll
        for (int j = 0; j < 2; ++j) {
            const int f = kb * 16 + (2 * w + j);
            w1h[kb][j] = ((const half8*)W1f)[f * 64 + lane];
            w1l[kb][j] = ((const half8*)W1l)[f * 64 + lane];
        }
        const int g = kb * 8 + w;
        w2h[kb] = ((const half8*)W2f)[g * 64 + lane];
        w2l[kb] = ((const half8*)W2l)[g * 64 + lane];
    }

#pragma unroll 1
    for (int l = 5; l >= 0; --l) {
        const int p0 = (1 << l) - 1, n = 1 << l;
        const int ns = (l == 5) ? 2 : 1;     // strips of 16 rows (uniform)

        // ---- GEMM1': H^T = W1^T @ X^T, bias-init, split f16 ----
        f32x4 d1[2][2];
#pragma unroll
        for (int s = 0; s < 2; ++s)
#pragma unroll
            for (int j = 0; j < 2; ++j)
                d1[s][j] = *(const f32x4*)(b1 + (2 * w + j) * 16 + q * 4);

#pragma unroll
        for (int kb = 0; kb < 8; ++kb) {
            const int k0  = kb * 32 + q * 8;        // 0..255, 8-aligned
            const int hi  = kb >> 2;                // which child half
            const int col = (kb & 3) * 32 + q * 8;  // col within child
#pragma unroll
            for (int s = 0; s < 2; ++s) {
                if (s >= ns) break;
                half8 xh, xl;
                if (l == 5) {
                    const int row = s * 16 + nl;
                    const float* Xr = embs + (size_t)(63 + 2 * row) * EMB + k0;
                    f32x4 u = *(const f32x4*)Xr;
                    f32x4 v = *(const f32x4*)(Xr + 4);
#pragma unroll
                    for (int r = 0; r < 4; ++r) {
                        _Float16 a = (_Float16)u[r];
                        xh[r] = a; xl[r] = (_Float16)(u[r] - (float)a);
                        _Float16 b = (_Float16)v[r];
                        xh[r + 4] = b; xl[r + 4] = (_Float16)(v[r] - (float)b);
                    }
                } else {
                    // child = (2*row + hi) & 31 = 2*nl + hi  (independent of s)
                    xh = *(const half8*)&Obh[hi][nl][col];
                    xl = *(const half8*)&Obl[hi][nl][col];
                }
#pragma unroll
                for (int j = 0; j < 2; ++j) {
                    d1[s][j] = __builtin_amdgcn_mfma_f32_16x16x32_f16(w1h[kb][j], xh, d1[s][j], 0, 0, 0);
                    d1[s][j] = __builtin_amdgcn_mfma_f32_16x16x32_f16(w1h[kb][j], xl, d1[s][j], 0, 0, 0);
                    d1[s][j] = __builtin_amdgcn_mfma_f32_16x16x32_f16(w1l[kb][j], xh, d1[s][j], 0, 0, 0);
                }
            }
        }

        // ---- epilogue 1: lrelu, hi/lo f16, store H to LDS (cross-wave) ----
#pragma unroll
        for (int s = 0; s < 2; ++s) {
            if (s >= ns) break;
            const int row = s * 16 + nl;
#pragma unroll
            for (int j = 0; j < 2; ++j) {
                half4 hh4, hl4;
#pragma unroll
                for (int r = 0; r < 4; ++r) {
                    float x = d1[s][j][r];
                    x = x > 0.f ? x : 0.01f * x;
                    _Float16 a = (_Float16)x;
                    hh4[r] = a; hl4[r] = (_Float16)(x - (float)a);
                }
                const int cf = (2 * w + j) * 16 + q * 4;
                *(half4*)&Hsh[row][cf] = hh4;
                *(half4*)&Hsl[row][cf] = hl4;
            }
        }
        __syncthreads();

        // ---- GEMM2': O^T = W2^T @ H^T, split f16 ----
        f32x4 d2[2];
#pragma unroll
        for (int s = 0; s < 2; ++s)
            d2[s] = *(const f32x4*)(b2 + w * 16 + q * 4);

#pragma unroll
        for (int kb = 0; kb < 8; ++kb) {
#pragma unroll
            for (int s = 0; s < 2; ++s) {
                if (s >= ns) break;
                const int row = s * 16 + nl;
                half8 hh = *(const half8*)&Hsh[row][kb * 32 + q * 8];
                half8 hl = *(const half8*)&Hsl[row][kb * 32 + q * 8];
                d2[s] = __builtin_amdgcn_mfma_f32_16x16x32_f16(w2h[kb], hh, d2[s], 0, 0, 0);
                d2[s] = __builtin_amdgcn_mfma_f32_16x16x32_f16(w2h[kb], hl, d2[s], 0, 0, 0);
                d2[s] = __builtin_amdgcn_mfma_f32_16x16x32_f16(w2l[kb], hh, d2[s], 0, 0, 0);
            }
        }

        // ---- epilogue 2: lrelu; O to parity-split LDS + global for row<n ----
#pragma unroll
        for (int s = 0; s < 2; ++s) {
            if (s >= ns) break;
            const int row = s * 16 + nl;
            f32x4 o;
#pragma unroll
            for (int r = 0; r < 4; ++r) { float x = d2[s][r]; o[r] = x > 0.f ? x : 0.01f * x; }
            half4 oh4, ol4;
#pragma unroll
            for (int r = 0; r < 4; ++r) {
                _Float16 a = (_Float16)o[r];
                oh4[r] = a; ol4[r] = (_Float16)(o[r] - (float)a);
            }
            const int cf = w * 16 + q * 4;
            *(half4*)&Obh[row & 1][row >> 1][cf] = oh4;
            *(half4*)&Obl[row & 1][row >> 1][cf] = ol4;
            if (row < n)
                *(f32x4*)(embs + (size_t)(p0 + row) * EMB + cf) = o;
        }
        __syncthreads();
    }
}

// ---------------------------------------------------------------------------
extern "C" void kernel_launch(void* const* d_in, const int* in_sizes, int n_in,
                              void* d_out, int out_size, void* d_ws, size_t ws_size,
                              hipStream_t stream)
{
    const float* lv = (const float*)d_in[0];
    const float* We = (const float*)d_in[1];
    const float* be = (const float*)d_in[2];
    const float* W1 = (const float*)d_in[3];
    const float* b1 = (const float*)d_in[4];
    const float* W2 = (const float*)d_in[5];
    const float* b2 = (const float*)d_in[6];
    float* embs = (float*)d_out;

    _Float16* W1f = (_Float16*)d_ws;            // 65536 f16 = 128 KB
    _Float16* W2f = W1f + 65536;                // 32768 f16 =  64 KB
    _Float16* W1l = W2f + 32768;                // 65536 f16 = 128 KB
    _Float16* W2l = W1l + 65536;                // 32768 f16 =  64 KB  (384 KB total)

    prep_weights<<<48, 256, 0, stream>>>(W1, W2, W1f, W2f, W1l, W2l);
    leaf_embed<<<N_LEAVES / 16, 256, 0, stream>>>(lv, We, be, embs);
    upper_ladder<<<256, 512, 0, stream>>>(W1f, W2f, b1, b2, embs);
    mid_ladder<<<1, 512, 0, stream>>>(W1f, W2f, b1, b2, embs);
    tail_levels<<<1, 512, 0, stream>>>(W1f, W1l, W2f, W2l, b1, b2, embs);
}

// Round 5
// 455.447 us; speedup vs baseline: 1.8102x; 1.0164x over previous
//
#include <hip/hip_runtime.h>

#define DEPTH 18
#define EMB 128
#define HID 256
#define VAL 32
#define N_LEAVES (1 << DEPTH)
#define LEAF_START (N_LEAVES - 1)

typedef _Float16 half8 __attribute__((ext_vector_type(8)));
typedef _Float16 half4 __attribute__((ext_vector_type(4)));
typedef float f32x4 __attribute__((ext_vector_type(4)));

__device__ __forceinline__ float lrelu(float x) { return x > 0.f ? x : 0.01f * x; }

// ---------------------------------------------------------------------------
// Prep: swizzle W1 (256x256), W2 (256x128), We (32x128) into fp16 MFMA
// A-fragment order for the TRANSPOSED GEMMs (A = W^T, m = output col,
// k = contraction dim). Emits hi (f16 rounding) and lo (residual) frags.
// Frag lane layout (16x16x32): lane holds A[m = lane&15][k = (lane>>4)*8 + jj].
// We has k-depth 32 = exactly one MFMA step -> 8 col-tile frags.
// ---------------------------------------------------------------------------
__global__ __launch_bounds__(256) void prep_weights(
    const float* __restrict__ W1, const float* __restrict__ W2,
    const float* __restrict__ We,
    _Float16* __restrict__ W1f, _Float16* __restrict__ W2f,
    _Float16* __restrict__ W1l, _Float16* __restrict__ W2l,
    _Float16* __restrict__ Wef, _Float16* __restrict__ Wel)
{
    const int gid = blockIdx.x * 256 + threadIdx.x;   // 12800 total
    const int lane = gid & 63;
    const int nn = lane & 15, q = lane >> 4;
    if (gid < 8192) {
        const int f = gid >> 6, kb = f >> 4, jt = f & 15;
        half8 vh, vl;
#pragma unroll
        for (int jj = 0; jj < 8; ++jj) {
            float x = W1[(kb * 32 + q * 8 + jj) * HID + jt * 16 + nn];
            _Float16 h = (_Float16)x;
            vh[jj] = h;
            vl[jj] = (_Float16)(x - (float)h);
        }
        *((half8*)W1f + gid) = vh;
        *((half8*)W1l + gid) = vl;
    } else if (gid < 12288) {
        const int g = gid - 8192;
        const int f = g >> 6, kb = f >> 3, ct = f & 7;
        half8 vh, vl;
#pragma unroll
        for (int jj = 0; jj < 8; ++jj) {
            float x = W2[(kb * 32 + q * 8 + jj) * EMB + ct * 16 + nn];
            _Float16 h = (_Float16)x;
            vh[jj] = h;
            vl[jj] = (_Float16)(x - (float)h);
        }
        *((half8*)W2f + g) = vh;
        *((half8*)W2l + g) = vl;
    } else {
        const int g = gid - 12288;          // 0..511
        const int ct = g >> 6;              // col tile 0..7
        half8 vh, vl;
#pragma unroll
        for (int jj = 0; jj < 8; ++jj) {
            float x = We[(q * 8 + jj) * EMB + ct * 16 + nn];
            _Float16 h = (_Float16)x;
            vh[jj] = h;
            vl[jj] = (_Float16)(x - (float)h);
        }
        *((half8*)Wef + g) = vh;
        *((half8*)Wel + g) = vl;
    }
}

// ---------------------------------------------------------------------------
// Strip compute: the post-stage portion of a 64-parent-row strip (8 waves,
// wave w owns W1 hid tiles {2w,2w+1} and W2 out-col tile w, register-resident).
// Barrier placement identical to the round-4 strip64: sync (Xs ready) ->
// GEMM1 -> epi1 -> sync (Hs ready) -> GEMM2 -> epi2 -> sync (stores retired
// to same-CU L1/L2 before any dependent stage).
// ---------------------------------------------------------------------------
__device__ __forceinline__ void strip_compute(
    const half8 (&w1)[8][2], const half8 (&w2)[8],
    const f32x4 (&bb1)[2], const f32x4 bb2,
    float* __restrict__ embs, int p0, int r0,
    _Float16 (&Xs)[64][264], _Float16 (&Hs)[64][264],
    int w, int nl, int q)
{
    __syncthreads();                        // Xs ready

    // ---- GEMM1': H^T = W1^T @ X^T ----
    f32x4 d1[4][2];
#pragma unroll
    for (int s = 0; s < 4; ++s) { d1[s][0] = bb1[0]; d1[s][1] = bb1[1]; }
#pragma unroll
    for (int kb = 0; kb < 8; ++kb) {
#pragma unroll
        for (int s = 0; s < 4; ++s) {
            half8 x = *(const half8*)&Xs[s * 16 + nl][kb * 32 + q * 8];
            d1[s][0] = __builtin_amdgcn_mfma_f32_16x16x32_f16(w1[kb][0], x, d1[s][0], 0, 0, 0);
            d1[s][1] = __builtin_amdgcn_mfma_f32_16x16x32_f16(w1[kb][1], x, d1[s][1], 0, 0, 0);
        }
    }
    // ---- epilogue 1: lrelu -> f16 -> Hs (cross-wave exchange) ----
#pragma unroll
    for (int s = 0; s < 4; ++s) {
#pragma unroll
        for (int j = 0; j < 2; ++j) {
            half4 h;
#pragma unroll
            for (int r = 0; r < 4; ++r) {
                float x = d1[s][j][r];
                h[r] = (_Float16)(x > 0.f ? x : 0.01f * x);
            }
            *(half4*)&Hs[s * 16 + nl][(2 * w + j) * 16 + q * 4] = h;
        }
    }
    __syncthreads();                        // Hs ready

    // ---- GEMM2': O^T = W2^T @ H^T ----
    f32x4 d2[4];
#pragma unroll
    for (int s = 0; s < 4; ++s) d2[s] = bb2;
#pragma unroll
    for (int kb = 0; kb < 8; ++kb) {
#pragma unroll
        for (int s = 0; s < 4; ++s) {
            half8 h = *(const half8*)&Hs[s * 16 + nl][kb * 32 + q * 8];
            d2[s] = __builtin_amdgcn_mfma_f32_16x16x32_f16(w2[kb], h, d2[s], 0, 0, 0);
        }
    }
    // ---- epilogue 2: lrelu -> fp32 embs ----
    float* obase = embs + ((size_t)p0 + r0) * EMB;
#pragma unroll
    for (int s = 0; s < 4; ++s) {
        f32x4 o;
#pragma unroll
        for (int r = 0; r < 4; ++r) {
            float x = d2[s][r];
            o[r] = x > 0.f ? x : 0.01f * x;
        }
        *(f32x4*)(obase + (s * 16 + nl) * EMB + w * 16 + q * 4) = o;
    }
    __syncthreads();   // stores visible before next strip/level stages
}

// Classic global-read stage: children rows [2*r0, 2*r0+128) -> f16 Xs.
__device__ __forceinline__ void stage_global(
    const float* __restrict__ embs, int p0, int r0,
    _Float16 (&Xs)[64][264], int tid)
{
    const float4* src = (const float4*)(embs + ((size_t)(2 * p0 + 1) + 2 * (size_t)r0) * EMB);
#pragma unroll
    for (int i = 0; i < 8; ++i) {
        const int f = i * 512 + tid;       // 0..4095 float4s
        float4 v = src[f];
        half4 h;
        h[0] = (_Float16)v.x; h[1] = (_Float16)v.y;
        h[2] = (_Float16)v.z; h[3] = (_Float16)v.w;
        *(half4*)&Xs[f >> 6][(f & 63) * 4] = h;
    }
}

__device__ __forceinline__ void strip64(
    const half8 (&w1)[8][2], const half8 (&w2)[8],
    const f32x4 (&bb1)[2], const f32x4 bb2,
    float* __restrict__ embs, int p0, int r0,
    _Float16 (&Xs)[64][264], _Float16 (&Hs)[64][264],
    int tid, int w, int nl, int q)
{
    stage_global(embs, p0, r0, Xs, tid);
    strip_compute(w1, w2, bb1, bb2, embs, p0, r0, Xs, Hs, w, nl, q);
}

// ---------------------------------------------------------------------------
// Tree ladder: leaf embedding + levels 17..8 in one launch, NO grid sync.
// Block b owns the aligned subtree over level-17 rows [512b, 512b+512) and
// leaves [1024b, 1024b+1024) -> pure intra-block dependencies.
//
// NEW vs round 4: level-17 strips FUSE the leaf embedder. Instead of reading
// 128 MB of leaf embeddings back from HBM (written by the separate 90us
// issue-bound leaf_embed kernel), each strip computes
//   E^T = We^T @ LV^T   (split-precision MFMA: lvh*weh + lvl*weh + lvh*wel)
// from a 2KB/wave coalesced lv read, applies lrelu, stores fp32 leaf rows to
// embs (mandatory output) and f16 directly into Xs (parent-pair layout).
// MFMA sequence for levels 17..8 outputs is bit-identical to round 4.
// ---------------------------------------------------------------------------
__global__ __launch_bounds__(512) void tree_ladder(
    const _Float16* __restrict__ W1f, const _Float16* __restrict__ W2f,
    const _Float16* __restrict__ Wef, const _Float16* __restrict__ Wel,
    const float* __restrict__ lv, const float* __restrict__ be,
    const float* __restrict__ b1, const float* __restrict__ b2,
    float* __restrict__ embs)
{
    __shared__ alignas(16) _Float16 Xs[64][264];   // 33792 B
    __shared__ alignas(16) _Float16 Hs[64][264];   // 33792 B

    const int tid  = threadIdx.x;
    const int w    = tid >> 6;        // 0..7
    const int lane = tid & 63;
    const int nl   = lane & 15;
    const int q    = lane >> 4;
    const int b    = blockIdx.x;      // 0..255 subtree id

    // ---- one-time weight preload into registers ----
    half8 w1[8][2], w2[8];
#pragma unroll
    for (int kb = 0; kb < 8; ++kb) {
#pragma unroll
        for (int j = 0; j < 2; ++j)
            w1[kb][j] = ((const half8*)W1f)[(kb * 16 + 2 * w + j) * 64 + lane];
        w2[kb] = ((const half8*)W2f)[(kb * 8 + w) * 64 + lane];
    }
    const half8 wef = ((const half8*)Wef)[w * 64 + lane];
    const half8 wel = ((const half8*)Wel)[w * 64 + lane];
    f32x4 bb1[2], bb2, bbe;
#pragma unroll
    for (int j = 0; j < 2; ++j)
        bb1[j] = *(const f32x4*)(b1 + (2 * w + j) * 16 + q * 4);
    bb2 = *(const f32x4*)(b2 + w * 16 + q * 4);
    bbe = *(const f32x4*)(be + w * 16 + q * 4);

    // ---- level 17: 8 strips, fused leaf-embed staging ----
    {
        const int p0 = (1 << 17) - 1;          // 131071
#pragma unroll 1
        for (int t = 0; t < 8; ++t) {
            const int r0 = 512 * b + t * 64;
            // stage: leaves [2*r0, 2*r0+128): E = lrelu(lv @ We + be)
#pragma unroll
            for (int tile = 0; tile < 8; ++tile) {
                const int ll = tile * 16 + nl;             // leaf local 0..127
                const float* lvr = lv + ((size_t)2 * r0 + ll) * VAL + q * 8;
                f32x4 u = *(const f32x4*)lvr;
                f32x4 v = *(const f32x4*)(lvr + 4);
                half8 xh, xl;
#pragma unroll
                for (int r = 0; r < 4; ++r) {
                    _Float16 a = (_Float16)u[r];
                    xh[r] = a; xl[r] = (_Float16)(u[r] - (float)a);
                    _Float16 g = (_Float16)v[r];
                    xh[r + 4] = g; xl[r + 4] = (_Float16)(v[r] - (float)g);
                }
                f32x4 e = bbe;
                e = __builtin_amdgcn_mfma_f32_16x16x32_f16(wef, xh, e, 0, 0, 0);
                e = __builtin_amdgcn_mfma_f32_16x16x32_f16(wef, xl, e, 0, 0, 0);
                e = __builtin_amdgcn_mfma_f32_16x16x32_f16(wel, xh, e, 0, 0, 0);
                f32x4 o;
                half4 h4;
#pragma unroll
                for (int r = 0; r < 4; ++r) {
                    float x = e[r];
                    o[r] = x > 0.f ? x : 0.01f * x;
                    h4[r] = (_Float16)o[r];
                }
                // fp32 leaf row to output
                *(f32x4*)(embs + (size_t)(LEAF_START + 2 * r0 + ll) * EMB + w * 16 + q * 4) = o;
                // f16 into Xs, parent-pair layout: X[parent][childhalf*128 + col]
                *(half4*)&Xs[ll >> 1][(ll & 1) * 128 + w * 16 + q * 4] = h4;
            }
            strip_compute(w1, w2, bb1, bb2, embs, p0, r0, Xs, Hs, w, nl, q);
        }
    }

    // ---- levels 16..8 ----
#pragma unroll 1
    for (int l = 16; l >= 8; --l) {
        const int p0 = (1 << l) - 1;
        const int R  = 1 << (l - 8);           // rows per block at this level
        const int row0 = R * b;

        if (R >= 64) {
#pragma unroll 1
            for (int t = 0; t < (R >> 6); ++t)
                strip64(w1, w2, bb1, bb2, embs, p0, row0 + t * 64,
                        Xs, Hs, tid, w, nl, q);
        } else {
            const int ns = (R > 16) ? 2 : 1;   // 16-row tiles (R=32 -> 2)

            // ---- GEMM1': per-lane global X (same-CU L1/L2), hi-only f16 ----
            f32x4 d1[2][2];
#pragma unroll
            for (int s = 0; s < 2; ++s) { d1[s][0] = bb1[0]; d1[s][1] = bb1[1]; }
#pragma unroll
            for (int kb = 0; kb < 8; ++kb) {
#pragma unroll
                for (int s = 0; s < 2; ++s) {
                    if (s >= ns) break;
                    const int row = row0 + s * 16 + nl;   // may be garbage (>=R)
                    const float* Xr = embs + (size_t)(2 * (p0 + row) + 1) * EMB
                                    + kb * 32 + q * 8;
                    f32x4 u = *(const f32x4*)Xr;
                    f32x4 v = *(const f32x4*)(Xr + 4);
                    half8 x;
#pragma unroll
                    for (int r = 0; r < 4; ++r) {
                        x[r]     = (_Float16)u[r];
                        x[r + 4] = (_Float16)v[r];
                    }
                    d1[s][0] = __builtin_amdgcn_mfma_f32_16x16x32_f16(w1[kb][0], x, d1[s][0], 0, 0, 0);
                    d1[s][1] = __builtin_amdgcn_mfma_f32_16x16x32_f16(w1[kb][1], x, d1[s][1], 0, 0, 0);
                }
            }
            // ---- epilogue 1 (preceded by a barrier in all paths -> safe) ----
#pragma unroll
            for (int s = 0; s < 2; ++s) {
                if (s >= ns) break;
#pragma unroll
                for (int j = 0; j < 2; ++j) {
                    half4 h;
#pragma unroll
                    for (int r = 0; r < 4; ++r) {
                        float x = d1[s][j][r];
                        h[r] = (_Float16)(x > 0.f ? x : 0.01f * x);
                    }
                    *(half4*)&Hs[s * 16 + nl][(2 * w + j) * 16 + q * 4] = h;
                }
            }
            __syncthreads();                    // Hs ready

            // ---- GEMM2' ----
            f32x4 d2[2];
#pragma unroll
            for (int s = 0; s < 2; ++s) d2[s] = bb2;
#pragma unroll
            for (int kb = 0; kb < 8; ++kb) {
#pragma unroll
                for (int s = 0; s < 2; ++s) {
                    if (s >= ns) break;
                    half8 h = *(const half8*)&Hs[s * 16 + nl][kb * 32 + q * 8];
                    d2[s] = __builtin_amdgcn_mfma_f32_16x16x32_f16(w2[kb], h, d2[s], 0, 0, 0);
                }
            }
            // ---- epilogue 2: guarded fp32 writes (garbage rows dropped) ----
#pragma unroll
            for (int s = 0; s < 2; ++s) {
                if (s >= ns) break;
                const int idx = s * 16 + nl;
                f32x4 o;
#pragma unroll
                for (int r = 0; r < 4; ++r) {
                    float x = d2[s][r];
                    o[r] = x > 0.f ? x : 0.01f * x;
                }
                if (idx < R)
                    *(f32x4*)(embs + (size_t)(p0 + row0 + idx) * EMB + w * 16 + q * 4) = o;
            }
            __syncthreads();                    // level complete (L1/L2-visible)
        }
    }
}

// ---------------------------------------------------------------------------
// Mid ladder: levels 7,6 (one block, three strip64 calls). Children of level
// 7 come from tree_ladder (cross-kernel dispatch boundary -> visible);
// level 6's children come from this block's own level-7 strips (barrier'd).
// ---------------------------------------------------------------------------
__global__ __launch_bounds__(512) void mid_ladder(
    const _Float16* __restrict__ W1f, const _Float16* __restrict__ W2f,
    const float* __restrict__ b1, const float* __restrict__ b2,
    float* __restrict__ embs)
{
    __shared__ alignas(16) _Float16 Xs[64][264];
    __shared__ alignas(16) _Float16 Hs[64][264];

    const int tid  = threadIdx.x;
    const int w    = tid >> 6;
    const int lane = tid & 63;
    const int nl   = lane & 15;
    const int q    = lane >> 4;

    half8 w1[8][2], w2[8];
#pragma unroll
    for (int kb = 0; kb < 8; ++kb) {
#pragma unroll
        for (int j = 0; j < 2; ++j)
            w1[kb][j] = ((const half8*)W1f)[(kb * 16 + 2 * w + j) * 64 + lane];
        w2[kb] = ((const half8*)W2f)[(kb * 8 + w) * 64 + lane];
    }
    f32x4 bb1[2], bb2;
#pragma unroll
    for (int j = 0; j < 2; ++j)
        bb1[j] = *(const f32x4*)(b1 + (2 * w + j) * 16 + q * 4);
    bb2 = *(const f32x4*)(b2 + w * 16 + q * 4);

    strip64(w1, w2, bb1, bb2, embs, 127,  0, Xs, Hs, tid, w, nl, q);  // l=7 a
    strip64(w1, w2, bb1, bb2, embs, 127, 64, Xs, Hs, tid, w, nl, q);  // l=7 b
    strip64(w1, w2, bb1, bb2, embs,  63,  0, Xs, Hs, tid, w, nl, q);  // l=6
}

// ---------------------------------------------------------------------------
// Levels 5..0 (63 nodes) fused in ONE 8-wave block, split-precision f16 MFMA
// (acc += xh*wh + xl*wh + xh*wl -> ~fp32 accuracy, rel err ~2^-22).
// Weights REGISTER-RESIDENT (hi+lo), loaded once. Activations ping-pong in
// LDS as f16 hi/lo pairs. Unchanged since round 2 (measured ~40 us).
// ---------------------------------------------------------------------------
__global__ __launch_bounds__(512, 2) void tail_levels(
    const _Float16* __restrict__ W1f, const _Float16* __restrict__ W1l,
    const _Float16* __restrict__ W2f, const _Float16* __restrict__ W2l,
    const float* __restrict__ b1, const float* __restrict__ b2,
    float* __restrict__ embs)
{
    __shared__ alignas(16) _Float16 Hsh[32][264];      // 16896 B
    __shared__ alignas(16) _Float16 Hsl[32][264];      // 16896 B
    __shared__ alignas(16) _Float16 Obh[2][16][136];   //  8704 B
    __shared__ alignas(16) _Float16 Obl[2][16][136];   //  8704 B   (51.2 KB)

    const int tid  = threadIdx.x;
    const int w    = tid >> 6;        // 0..7
    const int lane = tid & 63;
    const int nl   = lane & 15;
    const int q    = lane >> 4;

    // ---- one-time weight preload into registers (static indexing only) ----
    half8 w1h[8][2], w1l[8][2], w2h[8], w2l[8];
#pragma unroll
    for (int kb = 0; kb < 8; ++kb) {
#pragma unroll
        for (int j = 0; j < 2; ++j) {
            const int f = kb * 16 + (2 * w + j);
            w1h[kb][j] = ((const half8*)W1f)[f * 64 + lane];
            w1l[kb][j] = ((const half8*)W1l)[f * 64 + lane];
        }
        const int g = kb * 8 + w;
        w2h[kb] = ((const half8*)W2f)[g * 64 + lane];
        w2l[kb] = ((const half8*)W2l)[g * 64 + lane];
    }

#pragma unroll 1
    for (int l = 5; l >= 0; --l) {
        const int p0 = (1 << l) - 1, n = 1 << l;
        const int ns = (l == 5) ? 2 : 1;     // strips of 16 rows (uniform)

        // ---- GEMM1': H^T = W1^T @ X^T, bias-init, split f16 ----
        f32x4 d1[2][2];
#pragma unroll
        for (int s = 0; s < 2; ++s)
#pragma unroll
            for (int j = 0; j < 2; ++j)
                d1[s][j] = *(const f32x4*)(b1 + (2 * w + j) * 16 + q * 4);

#pragma unroll
        for (int kb = 0; kb < 8; ++kb) {
            const int k0  = kb * 32 + q * 8;        // 0..255, 8-aligned
            const int hi  = kb >> 2;                // which child half
            const int col = (kb & 3) * 32 + q * 8;  // col within child
#pragma unroll
            for (int s = 0; s < 2; ++s) {
                if (s >= ns) break;
                half8 xh, xl;
                if (l == 5) {
                    const int row = s * 16 + nl;
                    const float* Xr = embs + (size_t)(63 + 2 * row) * EMB + k0;
                    f32x4 u = *(const f32x4*)Xr;
                    f32x4 v = *(const f32x4*)(Xr + 4);
#pragma unroll
                    for (int r = 0; r < 4; ++r) {
                        _Float16 a = (_Float16)u[r];
                        xh[r] = a; xl[r] = (_Float16)(u[r] - (float)a);
                        _Float16 b = (_Float16)v[r];
                        xh[r + 4] = b; xl[r + 4] = (_Float16)(v[r] - (float)b);
                    }
                } else {
                    // child = (2*row + hi) & 31 = 2*nl + hi  (independent of s)
                    xh = *(const half8*)&Obh[hi][nl][col];
                    xl = *(const half8*)&Obl[hi][nl][col];
                }
#pragma unroll
                for (int j = 0; j < 2; ++j) {
                    d1[s][j] = __builtin_amdgcn_mfma_f32_16x16x32_f16(w1h[kb][j], xh, d1[s][j], 0, 0, 0);
                    d1[s][j] = __builtin_amdgcn_mfma_f32_16x16x32_f16(w1h[kb][j], xl, d1[s][j], 0, 0, 0);
                    d1[s][j] = __builtin_amdgcn_mfma_f32_16x16x32_f16(w1l[kb][j], xh, d1[s][j], 0, 0, 0);
                }
            }
        }

        // ---- epilogue 1: lrelu, hi/lo f16, store H to LDS (cross-wave) ----
#pragma unroll
        for (int s = 0; s < 2; ++s) {
            if (s >= ns) break;
            const int row = s * 16 + nl;
#pragma unroll
            for (int j = 0; j < 2; ++j) {
                half4 hh4, hl4;
#pragma unroll
                for (int r = 0; r < 4; ++r) {
                    float x = d1[s][j][r];
                    x = x > 0.f ? x : 0.01f * x;
                    _Float16 a = (_Float16)x;
                    hh4[r] = a; hl4[r] = (_Float16)(x - (float)a);
                }
                const int cf = (2 * w + j) * 16 + q * 4;
                *(half4*)&Hsh[row][cf] = hh4;
                *(half4*)&Hsl[row][cf] = hl4;
            }
        }
        __syncthreads();

        // ---- GEMM2': O^T = W2^T @ H^T, split f16 ----
        f32x4 d2[2];
#pragma unroll
        for (int s = 0; s < 2; ++s)
            d2[s] = *(const f32x4*)(b2 + w * 16 + q * 4);

#pragma unroll
        for (int kb = 0; kb < 8; ++kb) {
#pragma unroll
            for (int s = 0; s < 2; ++s) {
                if (s >= ns) break;
                const int row = s * 16 + nl;
                half8 hh = *(const half8*)&Hsh[row][kb * 32 + q * 8];
                half8 hl = *(const half8*)&Hsl[row][kb * 32 + q * 8];
                d2[s] = __builtin_amdgcn_mfma_f32_16x16x32_f16(w2h[kb], hh, d2[s], 0, 0, 0);
                d2[s] = __builtin_amdgcn_mfma_f32_16x16x32_f16(w2h[kb], hl, d2[s], 0, 0, 0);
                d2[s] = __builtin_amdgcn_mfma_f32_16x16x32_f16(w2l[kb], hh, d2[s], 0, 0, 0);
            }
        }

        // ---- epilogue 2: lrelu; O to parity-split LDS + global for row<n ----
#pragma unroll
        for (int s = 0; s < 2; ++s) {
            if (s >= ns) break;
            const int row = s * 16 + nl;
            f32x4 o;
#pragma unroll
            for (int r = 0; r < 4; ++r) { float x = d2[s][r]; o[r] = x > 0.f ? x : 0.01f * x; }
            half4 oh4, ol4;
#pragma unroll
            for (int r = 0; r < 4; ++r) {
                _Float16 a = (_Float16)o[r];
                oh4[r] = a; ol4[r] = (_Float16)(o[r] - (float)a);
            }
            const int cf = w * 16 + q * 4;
            *(half4*)&Obh[row & 1][row >> 1][cf] = oh4;
            *(half4*)&Obl[row & 1][row >> 1][cf] = ol4;
            if (row < n)
                *(f32x4*)(embs + (size_t)(p0 + row) * EMB + cf) = o;
        }
        __syncthreads();
    }
}

// ---------------------------------------------------------------------------
extern "C" void kernel_launch(void* const* d_in, const int* in_sizes, int n_in,
                              void* d_out, int out_size, void* d_ws, size_t ws_size,
                              hipStream_t stream)
{
    const float* lv = (const float*)d_in[0];
    const float* We = (const float*)d_in[1];
    const float* be = (const float*)d_in[2];
    const float* W1 = (const float*)d_in[3];
    const float* b1 = (const float*)d_in[4];
    const float* W2 = (const float*)d_in[5];
    const float* b2 = (const float*)d_in[6];
    float* embs = (float*)d_out;

    _Float16* W1f = (_Float16*)d_ws;            // 65536 f16 = 128 KB
    _Float16* W2f = W1f + 65536;                // 32768 f16 =  64 KB
    _Float16* W1l = W2f + 32768;                // 65536 f16 = 128 KB
    _Float16* W2l = W1l + 65536;                // 32768 f16 =  64 KB
    _Float16* Wef = W2l + 32768;                //  4096 f16 =   8 KB
    _Float16* Wel = Wef + 4096;                 //  4096 f16 =   8 KB  (400 KB)

    prep_weights<<<50, 256, 0, stream>>>(W1, W2, We, W1f, W2f, W1l, W2l, Wef, Wel);
    tree_ladder<<<256, 512, 0, stream>>>(W1f, W2f, Wef, Wel, lv, be, b1, b2, embs);
    mid_ladder<<<1, 512, 0, stream>>>(W1f, W2f, b1, b2, embs);
    tail_levels<<<1, 512, 0, stream>>>(W1f, W1l, W2f, W2l, b1, b2, embs);
}